// Round 7
// baseline (173.769 us; speedup 1.0000x reference)
//
#include <hip/hip_runtime.h>

#define N_NODES 50000
#define N_EDGES 600000
#define N_REL 8
#define D_IN 128
#define D_OUT 16
#define NC 144      // 8 relation col-groups + root
#define MAXDEG 64   // P(deg>64) ~ 1e-25 for Poisson(12); guarded

typedef __attribute__((ext_vector_type(8))) short bf16x8;
typedef __attribute__((ext_vector_type(4))) float f32x4;

#define COUNT_BLOCKS  ((N_EDGES + 255) / 256)    // 2344 (count + scatter fused)
#define WBUILD_BLOCKS ((NC * D_IN + 255) / 256)  // 72
#define PREP0_BLOCKS  (COUNT_BLOCKS + WBUILD_BLOCKS)
#define GEMM_BLOCKS   ((N_NODES + 63) / 64)      // 782 (64 nodes/block)
#define ACC_BLOCKS    (N_NODES / 4)              // 12500 (1 dst per wave)

__device__ __forceinline__ unsigned short f2bf(float f) {  // RNE
    unsigned u = __float_as_uint(f);
    return (unsigned short)((u + 0x7FFF + ((u >> 16) & 1)) >> 16);
}
__device__ __forceinline__ float bf2f(unsigned short h) {
    return __uint_as_float((unsigned)h << 16);
}
// LDS swizzle: row c = byte>>8 (256 B rows); XOR (c&7)<<4 keeps 16B align.
__device__ __forceinline__ int swz(int byte) { return byte ^ (((byte >> 8) & 7) << 4); }

// -------- prep0: fused {per-(dst,rel) count + CSR-bucket scatter} + WallT --------
__global__ __launch_bounds__(256) void prep0(const float* __restrict__ W,
                                             const float* __restrict__ root,
                                             const int* __restrict__ ei,
                                             const int* __restrict__ et,
                                             int* __restrict__ cnt,
                                             int* __restrict__ cursor,
                                             int* __restrict__ recs,
                                             unsigned short* __restrict__ WallT) {
    int b = blockIdx.x;
    if (b < COUNT_BLOCKS) {
        int e = b * 256 + threadIdx.x;
        if (e < N_EDGES) {
            int src = ei[e];
            int dst = ei[N_EDGES + e];
            int rel = et[e];
            atomicAdd(&cnt[dst * N_REL + rel], 1);
            int slot = atomicAdd(&cursor[dst], 1);
            if (slot < MAXDEG)
                recs[dst * MAXDEG + slot] = (src << 3) | rel;
        }
    } else {
        // WallT[c][k] = (g<8 ? W[g][k][o] : root[k][o]), c = g*16+o
        int t = (b - COUNT_BLOCKS) * 256 + threadIdx.x;
        if (t < NC * D_IN) {
            int c = t >> 7, k = t & 127;
            int g = c >> 4, o = c & 15;
            float v = (g < N_REL) ? W[(g * D_IN + k) * D_OUT + o]
                                  : root[k * D_OUT + o];
            WallT[t] = f2bf(v);
        }
    }
}

// -------- prep1: MFMA GEMM [64 nodes/block] x [144 cols], f32 x in-register cvt --------
// A-frag: lane holds x[n0+(l&15)][(l>>4)*8 + s*32 + j] cvt'd to bf16.
// B-frag from swizzled LDS. C/D: col=lane&15, row=(lane>>4)*4+j (m89 layout).
__global__ __launch_bounds__(256) void prep1(const float* __restrict__ x,
                                             const unsigned short* __restrict__ WallT,
                                             const float* __restrict__ bias,
                                             unsigned short* __restrict__ xW,
                                             float* __restrict__ out) {
    __shared__ unsigned short wlds[NC * D_IN];  // 36864 B
    {
        const float4* src = (const float4*)WallT;
        for (int i = threadIdx.x; i < NC * D_IN / 8; i += 256)
            *(float4*)((char*)wlds + swz(i * 16)) = src[i];
    }
    __syncthreads();

    int wave = threadIdx.x >> 6, lane = threadIdx.x & 63;
    int n0 = blockIdx.x * 64 + wave * 16;
    if (n0 >= N_NODES) return;
    int col = lane & 15, kg = lane >> 4;

    const float* xrow = x + (size_t)(n0 + col) * D_IN + kg * 8;
    bf16x8 afr[4];
#pragma unroll
    for (int s = 0; s < 4; ++s) {
        float4 lo = *(const float4*)(xrow + s * 32);
        float4 hi = *(const float4*)(xrow + s * 32 + 4);
        bf16x8 f;
        f[0] = (short)f2bf(lo.x); f[1] = (short)f2bf(lo.y);
        f[2] = (short)f2bf(lo.z); f[3] = (short)f2bf(lo.w);
        f[4] = (short)f2bf(hi.x); f[5] = (short)f2bf(hi.y);
        f[6] = (short)f2bf(hi.z); f[7] = (short)f2bf(hi.w);
        afr[s] = f;
    }
    float bv = bias[col];

#pragma unroll
    for (int ct = 0; ct < 9; ++ct) {
        int c = ct * 16 + col;
        f32x4 acc = {0.f, 0.f, 0.f, 0.f};
#pragma unroll
        for (int s = 0; s < 4; ++s) {
            bf16x8 bfr = *(const bf16x8*)((const char*)wlds +
                                          swz(c * 256 + kg * 16 + s * 64));
            acc = __builtin_amdgcn_mfma_f32_16x16x32_bf16(afr[s], bfr, acc, 0, 0, 0);
        }
        if (ct < 8) {
#pragma unroll
            for (int j = 0; j < 4; ++j)
                xW[(size_t)(n0 + kg * 4 + j) * D_IN + ct * 16 + col] = f2bf(acc[j]);
        } else {
#pragma unroll
            for (int j = 0; j < 4; ++j)
                out[(size_t)(n0 + kg * 4 + j) * D_OUT + col] = acc[j] + bv;
        }
    }
}

// -------- accum: one dst per wave; 4 edge-slots x 16 output lanes; no atomics --------
__global__ __launch_bounds__(256) void accum(const unsigned short* __restrict__ xW,
                                             const int* __restrict__ recs,
                                             const int* __restrict__ cnt,
                                             float* __restrict__ out) {
    int dst = blockIdx.x * 4 + (threadIdx.x >> 6);  // grid exact: 12500*4 = 50000
    int lane = threadIdx.x & 63;
    int o = lane & 15, es = lane >> 4;

    // deg = sum_r cnt[dst*8+r] via 8-lane butterfly (coalesced 32B line)
    int deg = cnt[dst * N_REL + (lane & 7)];
    deg += __shfl_xor(deg, 1);
    deg += __shfl_xor(deg, 2);
    deg += __shfl_xor(deg, 4);
    if (deg > MAXDEG) deg = MAXDEG;

    float acc = 0.f;
    for (int j = es; j < deg; j += 4) {
        int rec = recs[dst * MAXDEG + j];      // broadcast within 16-lane subgroup
        int rel = rec & 7, src = rec >> 3;
        float invc = __builtin_amdgcn_rcpf((float)cnt[dst * N_REL + rel]);
        acc += bf2f(xW[(size_t)src * D_IN + rel * D_OUT + o]) * invc;
    }
    acc += __shfl_xor(acc, 16);  // reduce the 4 edge-slots
    acc += __shfl_xor(acc, 32);
    if (lane < 16) out[(size_t)dst * D_OUT + o] += acc;  // exclusive owner: no atomic
}

extern "C" void kernel_launch(void* const* d_in, const int* in_sizes, int n_in,
                              void* d_out, int out_size, void* d_ws, size_t ws_size,
                              hipStream_t stream) {
    const float* x    = (const float*)d_in[0];
    const float* W    = (const float*)d_in[1];
    const float* root = (const float*)d_in[2];
    const float* bias = (const float*)d_in[3];
    const int* ei     = (const int*)d_in[4];
    const int* et     = (const int*)d_in[5];
    float* out = (float*)d_out;

    char* ws = (char*)d_ws;
    int* cnt    = (int*)ws;            ws += (size_t)N_NODES * N_REL * 4;    // 1.6 MB
    int* cursor = (int*)ws;            ws += (size_t)N_NODES * 4;            // 0.2 MB (adjacent to cnt)
    int* recs   = (int*)ws;            ws += (size_t)N_NODES * MAXDEG * 4;   // 12.8 MB
    unsigned short* xW = (unsigned short*)ws;  ws += (size_t)N_NODES * D_IN * 2;  // 12.8 MB
    unsigned short* WallT = (unsigned short*)ws;                             // 36.9 KB

    // one memset covers cnt + cursor (contiguous)
    hipMemsetAsync(cnt, 0, (size_t)(N_NODES * N_REL + N_NODES) * 4, stream);
    prep0<<<PREP0_BLOCKS, 256, 0, stream>>>(W, root, ei, et, cnt, cursor, recs, WallT);
    prep1<<<GEMM_BLOCKS, 256, 0, stream>>>(x, WallT, bias, xW, out);
    accum<<<ACC_BLOCKS, 256, 0, stream>>>(xW, recs, cnt, out);
}

// Round 9
// 142.487 us; speedup vs baseline: 1.2195x; 1.2195x over previous
//
#include <hip/hip_runtime.h>

#define N_NODES 50000
#define N_EDGES 600000
#define N_REL 8
#define D_IN 128
#define D_OUT 16
#define NC 144   // 8 relation col-groups + root

typedef __attribute__((ext_vector_type(8))) short bf16x8;
typedef __attribute__((ext_vector_type(4))) float f32x4;

#define GEMM_BLOCKS  ((N_NODES + 63) / 64)          // 782 (64 nodes/block)
#define COUNT_BLOCKS ((N_EDGES + 255) / 256)        // 2344
#define K1_BLOCKS    (GEMM_BLOCKS + COUNT_BLOCKS)   // 3126
#define EDGE_BLOCKS  ((N_EDGES / 64 + 3) / 4)       // 2344 (64 edges/wave)

__device__ __forceinline__ unsigned short f2bf(float f) {  // RNE
    unsigned u = __float_as_uint(f);
    return (unsigned short)((u + 0x7FFF + ((u >> 16) & 1)) >> 16);
}
__device__ __forceinline__ float bf2f(unsigned short h) {
    return __uint_as_float((unsigned)h << 16);
}
// LDS swizzle: row c = byte>>8 (256 B rows); XOR (c&7)<<4 keeps 16B align.
__device__ __forceinline__ int swz(int byte) { return byte ^ (((byte >> 8) & 7) << 4); }

// -------- k1: {MFMA GEMM blocks} + {edge-count blocks} in one grid --------
// GEMM blocks (0..781): convert W/root f32 -> bf16 LDS tile inline (74 KB
// L2-resident source, no global WallT), then per wave a 16-node x 144-col
// tile via mfma_f32_16x16x32_bf16. Count blocks (782..3125): fire-and-forget
// int atomics into cnt — latency hides under GEMM compute on other CUs.
__global__ __launch_bounds__(256) void k1(const float* __restrict__ x,
                                          const float* __restrict__ W,
                                          const float* __restrict__ root,
                                          const float* __restrict__ bias,
                                          const int* __restrict__ ei,
                                          const int* __restrict__ et,
                                          int* __restrict__ cnt,
                                          unsigned short* __restrict__ xW,
                                          float* __restrict__ out) {
    __shared__ unsigned short wlds[NC * D_IN];  // 36864 B
    int b = blockIdx.x;
    if (b >= GEMM_BLOCKS) {
        int e = (b - GEMM_BLOCKS) * 256 + threadIdx.x;
        if (e < N_EDGES)
            atomicAdd(&cnt[ei[N_EDGES + e] * N_REL + et[e]], 1);
        return;
    }

    // inline W build: linear coalesced f32 reads, swizzled bf16 LDS stores
    for (int t = threadIdx.x; t < NC * D_IN; t += 256) {
        float v; int c, k;
        if (t < N_REL * D_IN * D_OUT) {           // 16384 = W elems
            v = W[t];
            int o = t & 15, gk = t >> 4;          // t = (g*128+k)*16 + o
            k = gk & 127;
            c = (gk >> 7) * 16 + o;
        } else {                                   // root: 2048 elems
            int u = t - N_REL * D_IN * D_OUT;      // u = k*16 + o
            v = root[u];
            k = u >> 4;
            c = 128 + (u & 15);
        }
        *(unsigned short*)((char*)wlds + swz(c * 256 + k * 2)) = f2bf(v);
    }
    __syncthreads();

    int wave = threadIdx.x >> 6, lane = threadIdx.x & 63;
    int n0 = b * 64 + wave * 16;
    if (n0 >= N_NODES) return;
    int col = lane & 15, kg = lane >> 4;

    // A-frags: f32 x rows, in-register bf16 convert (no x_bf intermediate)
    const float* xrow = x + (size_t)(n0 + col) * D_IN + kg * 8;
    bf16x8 afr[4];
#pragma unroll
    for (int s = 0; s < 4; ++s) {
        float4 lo = *(const float4*)(xrow + s * 32);
        float4 hi = *(const float4*)(xrow + s * 32 + 4);
        bf16x8 f;
        f[0] = (short)f2bf(lo.x); f[1] = (short)f2bf(lo.y);
        f[2] = (short)f2bf(lo.z); f[3] = (short)f2bf(lo.w);
        f[4] = (short)f2bf(hi.x); f[5] = (short)f2bf(hi.y);
        f[6] = (short)f2bf(hi.z); f[7] = (short)f2bf(hi.w);
        afr[s] = f;
    }
    float bv = bias[col];

#pragma unroll
    for (int ct = 0; ct < 9; ++ct) {
        int c = ct * 16 + col;
        f32x4 acc = {0.f, 0.f, 0.f, 0.f};
#pragma unroll
        for (int s = 0; s < 4; ++s) {
            bf16x8 bfr = *(const bf16x8*)((const char*)wlds +
                                          swz(c * 256 + kg * 16 + s * 64));
            acc = __builtin_amdgcn_mfma_f32_16x16x32_bf16(afr[s], bfr, acc, 0, 0, 0);
        }
        if (ct < 8) {
#pragma unroll
            for (int j = 0; j < 4; ++j)
                xW[(size_t)(n0 + kg * 4 + j) * D_IN + ct * 16 + col] = f2bf(acc[j]);
        } else {
#pragma unroll
            for (int j = 0; j < 4; ++j)
                out[(size_t)(n0 + kg * 4 + j) * D_OUT + col] = acc[j] + bv;
        }
    }
}

// -------- edge: out[dst,o] += bf2f(xW[src, rel*16+o]) / cnt[dst,rel] --------
// Round-6-proven structure: 16 lanes/edge; each slot owns 16 contiguous
// edges; int4 index loads; 4-edge chunks; plain fire-and-forget atomicAdd.
__global__ __launch_bounds__(256) void edge_k(const unsigned short* __restrict__ xW,
                                              const int* __restrict__ ei,
                                              const int* __restrict__ et,
                                              const int* __restrict__ cnt,
                                              float* __restrict__ out) {
    int wid = (blockIdx.x * 256 + threadIdx.x) >> 6;
    int lane = threadIdx.x & 63;
    int s = lane >> 4, o = lane & 15;
    int e0 = wid * 64 + s * 16;
    if (e0 >= N_EDGES) return;
#pragma unroll 2
    for (int k = 0; k < 4; ++k) {
        int4 s4 = *(const int4*)(ei + e0 + k * 4);
        int4 d4 = *(const int4*)(ei + N_EDGES + e0 + k * 4);
        int4 r4 = *(const int4*)(et + e0 + k * 4);
        float v0 = bf2f(xW[(size_t)s4.x * D_IN + r4.x * D_OUT + o]);
        float v1 = bf2f(xW[(size_t)s4.y * D_IN + r4.y * D_OUT + o]);
        float v2 = bf2f(xW[(size_t)s4.z * D_IN + r4.z * D_OUT + o]);
        float v3 = bf2f(xW[(size_t)s4.w * D_IN + r4.w * D_OUT + o]);
        float c0 = (float)cnt[d4.x * N_REL + r4.x];
        float c1 = (float)cnt[d4.y * N_REL + r4.y];
        float c2 = (float)cnt[d4.z * N_REL + r4.z];
        float c3 = (float)cnt[d4.w * N_REL + r4.w];
        atomicAdd(&out[(size_t)d4.x * D_OUT + o], v0 * __builtin_amdgcn_rcpf(c0));
        atomicAdd(&out[(size_t)d4.y * D_OUT + o], v1 * __builtin_amdgcn_rcpf(c1));
        atomicAdd(&out[(size_t)d4.z * D_OUT + o], v2 * __builtin_amdgcn_rcpf(c2));
        atomicAdd(&out[(size_t)d4.w * D_OUT + o], v3 * __builtin_amdgcn_rcpf(c3));
    }
}

extern "C" void kernel_launch(void* const* d_in, const int* in_sizes, int n_in,
                              void* d_out, int out_size, void* d_ws, size_t ws_size,
                              hipStream_t stream) {
    const float* x    = (const float*)d_in[0];
    const float* W    = (const float*)d_in[1];
    const float* root = (const float*)d_in[2];
    const float* bias = (const float*)d_in[3];
    const int* ei     = (const int*)d_in[4];
    const int* et     = (const int*)d_in[5];
    float* out = (float*)d_out;

    char* ws = (char*)d_ws;
    int* cnt = (int*)ws;                       ws += (size_t)N_NODES * N_REL * 4;  // 1.6 MB
    unsigned short* xW = (unsigned short*)ws;  // 12.8 MB

    hipMemsetAsync(cnt, 0, (size_t)N_NODES * N_REL * 4, stream);
    k1<<<K1_BLOCKS, 256, 0, stream>>>(x, W, root, bias, ei, et, cnt, xW, out);
    edge_k<<<EDGE_BLOCKS, 256, 0, stream>>>(xW, ei, et, cnt, out);
}